// Round 15
// baseline (3233.773 us; speedup 1.0000x reference)
//
#include <hip/hip_runtime.h>
#include <hip/hip_bf16.h>
#include <stdint.h>

// SNN forward (snntorch Leaky, subtract reset), T=1024 B=128 NIN=256 HID=1024.
// d_out: out_spikes [T,B,2] | hidden_spikes [T,B,HID] | mem2_f [B,2]
//
// Round-15: occupancy restructure. R14 analysis: no pipe >45% busy; k_snn is
// latency-bound at 2 waves/SIMD (LDS-capped). New geometry: wave = 8 t-groups
// x 8 lanes x 8 quads (32 j); grid = 32 bg x 32 jc = 1024 wgs -> 4 wg/CU =
// 4 waves/SIMD. Tile shrunk via ROW SPLIT: k_pack writes two ascending lists
// per (t,b): rows<152 (gathered from a 153-row x 8-quad LDS tile, 19.6KB) and
// rows>=152 (via the proven 4-slot VMEM issue-ahead window from L2-resident
// W1T). lo-list then hi-list = strictly ascending i -> bit-exact (absmax 0.0
// rounds 1-14). Zero rows: LDS row 152, global row 256 for tail predication.
// k_h2/k_scan/k_transpose unchanged.

#define TT  1024
#define BB  128
#define NIN 256
#define HID 1024
#define SPLITR 152

#define OFF_HID  262144ULL
#define OFF_MEM2 134479872ULL

typedef float f4 __attribute__((ext_vector_type(4)));

// W1T: 257 rows (rows 0..255 = transpose, row 256 = zeros)
__global__ __launch_bounds__(256) void k_transpose(const float* __restrict__ W1,
                                                   float* __restrict__ W1T) {
    int idx = blockIdx.x * 256 + threadIdx.x;     // 263168 = 257*1024
    if (idx >= 257 * 1024) return;
    int j = idx & (HID - 1);
    int i = idx >> 10;
    W1T[(size_t)i * HID + j] = (i < NIN) ? W1[(size_t)j * NIN + i] : 0.0f;
}

// Two ascending lists per (t,b): lo (i<152) and hi (i>=152), 48 slots each,
// packed in a 128B block: [lo 48B | hi 48B | pad 32B]. cnt = cntLo | cntHi<<16.
__global__ __launch_bounds__(256) void k_pack(const float* __restrict__ x,
                                              unsigned* __restrict__ cntArr,
                                              unsigned char* __restrict__ idxArr) {
    size_t tb = blockIdx.x;                       // T*B blocks, 256 threads = i
    int tid = threadIdx.x, lane = tid & 63, w = tid >> 6;
    float v = x[tb * NIN + tid];
    bool act  = v > 0.5f;
    bool isLo = tid < SPLITR;
    unsigned long long mLo = __ballot(act && isLo);
    unsigned long long mHi = __ballot(act && !isLo);
    __shared__ unsigned wcLo[4], wcHi[4];
    __shared__ unsigned char sIdx[96];
    if (lane == 0) { wcLo[w] = (unsigned)__popcll(mLo); wcHi[w] = (unsigned)__popcll(mHi); }
    __syncthreads();
    unsigned offLo = 0, offHi = 0;
#pragma unroll
    for (int k = 0; k < 4; ++k) if (k < w) { offLo += wcLo[k]; offHi += wcHi[k]; }
    unsigned cntLo = wcLo[0] + wcLo[1] + wcLo[2] + wcLo[3];
    unsigned cntHi = wcHi[0] + wcHi[1] + wcHi[2] + wcHi[3];
    unsigned long long below = (1ull << lane) - 1;
    unsigned rLo = offLo + (unsigned)__popcll(mLo & below);
    unsigned rHi = offHi + (unsigned)__popcll(mHi & below);
    if (act && isLo  && rLo < 48) sIdx[rLo]      = (unsigned char)tid;
    if (act && !isLo && rHi < 48) sIdx[48 + rHi] = (unsigned char)tid;
    __syncthreads();
    if (tid < 24) ((unsigned*)(idxArr + tb * 128))[tid] = ((const unsigned*)sIdx)[tid];
    if (tid == 0) cntArr[tb] = cntLo | (cntHi << 16);
}

// Wave = one b: 8 t-groups (s=lane>>3) x 8 quads (q=lane&7) = 32 j, 8 t's per
// iter. Workgroup = 4 waves = 4 b's sharing the 153x8-f4 tile (rows 0..151 of
// the jc-slice + zero row 152). Grid = 32 bg x 32 jc = 1024 wgs -> 4 wg/CU.
__global__ __launch_bounds__(256, 4) void k_snn(const float* __restrict__ W1T,
                                                const unsigned* __restrict__ cntArr,
                                                const unsigned char* __restrict__ idxArr,
                                                const float* __restrict__ x,
                                                const float* __restrict__ b1,
                                                float* __restrict__ outHid) {
#pragma clang fp contract(off)
    const int jc   = blockIdx.x & 31;
    const int bg   = blockIdx.x >> 5;
    const int tid  = threadIdx.x;
    const int lane = tid & 63;
    const int wave = tid >> 6;
    const int b    = (bg << 2) + wave;
    const int q    = lane & 7;                    // quad (4 j) within 32-j chunk
    const int s    = lane >> 3;                   // t-subgroup 0..7
    const int jq   = (jc << 5) + (q << 2);
    const int jq4  = (jc << 3) + q;               // f4 index within a W1T row
    const bool sb0 = (s & 1) != 0, sb1 = (s & 2) != 0, sb2 = (s & 4) != 0;

    __shared__ f4 sW4[153 * 8];                   // 19.1 KB; row 152 = zeros
    __shared__ f4 sEx[4][64];                     // per-wave exchange (4 KB)
    const f4* __restrict__ W1Tf4 = reinterpret_cast<const f4*>(W1T);

    for (int p = tid; p < 153 * 8; p += 256) {
        int row = p >> 3, qq = p & 7;
        f4 z; z.x = 0.f; z.y = 0.f; z.z = 0.f; z.w = 0.f;
        sW4[p] = (row < SPLITR) ? W1Tf4[row * 256 + (jc << 3) + qq] : z;
    }
    __syncthreads();

    f4 mem4; mem4.x = 0.f; mem4.y = 0.f; mem4.z = 0.f; mem4.w = 0.f;
    const f4 bs = *reinterpret_cast<const f4*>(b1 + jq);
    const int ub = __builtin_amdgcn_readfirstlane(b);

    // per-lane running byte offsets into the 128B list blocks (group s -> t+s)
    unsigned offBlk = (unsigned)((s * BB + ub) * 128);
    unsigned offCnt = (unsigned)((s * BB + ub) * 4);
    const unsigned stB = 8u * BB * 128u;
    const unsigned stC = 8u * BB * 4u;

    unsigned cnt_v  = *(const unsigned*)((const char*)cntArr + offCnt);
    unsigned vLoA_v = *(const unsigned*)(idxArr + offBlk + (q << 2));          // lo dw 0-7
    unsigned vLoB_v = *(const unsigned*)(idxArr + offBlk + 32 + ((q & 3) << 2)); // lo dw 8-11
    unsigned vHiA_v = *(const unsigned*)(idxArr + offBlk + 48 + (q << 2));     // hi dw 0-7
    unsigned vHiB_v = *(const unsigned*)(idxArr + offBlk + 80 + ((q & 3) << 2)); // hi dw 8-11

    float* outP = outHid + ((size_t)s * BB + b) * HID + jq;
    const size_t outStep = (size_t)8 * BB * HID;

#define RL(v, l) ((unsigned)__builtin_amdgcn_readlane((int)(v), (l)))
    // broadcast group-g's dword kd to all its lanes: value lives in lane g*8+kd
#define FETCH8(vreg, kd, dOut) do {                                             \
        unsigned e0_=RL(vreg,(kd)),    e1_=RL(vreg,8+(kd)),                     \
                 e2_=RL(vreg,16+(kd)), e3_=RL(vreg,24+(kd)),                    \
                 e4_=RL(vreg,32+(kd)), e5_=RL(vreg,40+(kd)),                    \
                 e6_=RL(vreg,48+(kd)), e7_=RL(vreg,56+(kd));                    \
        unsigned x0_ = sb0 ? e1_ : e0_, x1_ = sb0 ? e3_ : e2_;                  \
        unsigned x2_ = sb0 ? e5_ : e4_, x3_ = sb0 ? e7_ : e6_;                  \
        unsigned y0_ = sb1 ? x1_ : x0_, y1_ = sb1 ? x3_ : x2_;                  \
        dOut = sb2 ? y1_ : y0_;                                                 \
    } while (0)

#define GLO4(d, kd) do {                                                        \
        _Pragma("unroll")                                                       \
        for (int i2 = 0; i2 < 4; ++i2) {                                        \
            unsigned r_ = ((d) >> (8 * i2)) & 255u;                             \
            r_ = ((unsigned)((kd) * 4 + i2) < mylimLo) ? r_ : (unsigned)SPLITR; \
            h4 += sW4[r_ * 8 + q];                                              \
        }                                                                       \
    } while (0)

#define FETCH_HI(kk, d) do {                                                    \
        if ((kk) < 8) FETCH8(vHiA, (kk), d);                                    \
        else          FETCH8(vHiB, (kk) - 8, d);                                \
    } while (0)

#define WISS(n) do {                                                            \
        if (isu < dwEndHi) {                                                    \
            unsigned d_; FETCH_HI(isu, d_);                                     \
            int kb_ = isu << 2;                                                 \
            unsigned r0_ = d_ & 255u, r1_ = (d_ >> 8) & 255u;                   \
            unsigned r2_ = (d_ >> 16) & 255u, r3_ = d_ >> 24;                   \
            r0_ = ((unsigned)(kb_    ) < mylimHi) ? r0_ : 256u;                 \
            r1_ = ((unsigned)(kb_ + 1) < mylimHi) ? r1_ : 256u;                 \
            r2_ = ((unsigned)(kb_ + 2) < mylimHi) ? r2_ : 256u;                 \
            r3_ = ((unsigned)(kb_ + 3) < mylimHi) ? r3_ : 256u;                 \
            w##n##a = W1Tf4[(r0_ << 8) + jq4];                                  \
            w##n##b = W1Tf4[(r1_ << 8) + jq4];                                  \
            w##n##c = W1Tf4[(r2_ << 8) + jq4];                                  \
            w##n##d = W1Tf4[(r3_ << 8) + jq4];                                  \
            ++isu;                                                              \
        }                                                                       \
    } while (0)

#define WCON(n) do { h4 += w##n##a; h4 += w##n##b; h4 += w##n##c; h4 += w##n##d; } while (0)

#define MSTEP(ev, spk) {                                                        \
        f4 mm_ = 0.9f * mem4; mm_ = mm_ + (ev);                                 \
        spk.x = (mm_.x - 1.0f > 0.0f) ? 1.0f : 0.0f;                            \
        spk.y = (mm_.y - 1.0f > 0.0f) ? 1.0f : 0.0f;                            \
        spk.z = (mm_.z - 1.0f > 0.0f) ? 1.0f : 0.0f;                            \
        spk.w = (mm_.w - 1.0f > 0.0f) ? 1.0f : 0.0f;                            \
        mem4 = mm_ - spk;                                                       \
    }

    for (int t = 0; t < TT; t += 8) {
        unsigned cnt = cnt_v;
        unsigned vLoA = vLoA_v, vLoB = vLoB_v, vHiA = vHiA_v, vHiB = vHiB_v;

        // prefetch t+8 (clamped via zero stride)
        unsigned stp = (t + 8 < TT) ? 1u : 0u;
        offBlk += stp * stB; offCnt += stp * stC;
        cnt_v  = *(const unsigned*)((const char*)cntArr + offCnt);
        vLoA_v = *(const unsigned*)(idxArr + offBlk + (q << 2));
        vLoB_v = *(const unsigned*)(idxArr + offBlk + 32 + ((q & 3) << 2));
        vHiA_v = *(const unsigned*)(idxArr + offBlk + 48 + (q << 2));
        vHiB_v = *(const unsigned*)(idxArr + offBlk + 80 + ((q & 3) << 2));

        unsigned rawLo = cnt & 0xFFFFu, rawHi = cnt >> 16;
        unsigned mylimLo = rawLo < 48u ? rawLo : 48u;
        unsigned mylimHi = rawHi < 48u ? rawHi : 48u;
        int ml = (int)mylimLo;
        ml = max(ml, __shfl_xor(ml, 8, 64));
        ml = max(ml, __shfl_xor(ml, 16, 64));
        ml = max(ml, __shfl_xor(ml, 32, 64));
        int dwEndLo = (ml + 3) >> 2;
        int mh = (int)mylimHi;
        mh = max(mh, __shfl_xor(mh, 8, 64));
        mh = max(mh, __shfl_xor(mh, 16, 64));
        mh = max(mh, __shfl_xor(mh, 32, 64));
        int dwEndHi = (mh + 3) >> 2;

        f4 e0, e1, e2, e3, e4, e5, e6, e7;        // h(t+0..t+7) for quad q
        bool ovf = (rawLo > 48u) || (rawHi > 48u);

        if (!__any((int)ovf)) {
            f4 h4 = bs;

            // hi-phase window: issue ahead so L2 latency hides under lo adds
            f4 w0a, w0b, w0c, w0d;
            f4 w1a, w1b, w1c, w1d;
            f4 w2a, w2b, w2c, w2d;
            f4 w3a, w3b, w3c, w3d;
            int isu = 0;
            WISS(0); WISS(1); WISS(2); WISS(3);

            // lo phase: LDS tile, dwords 0..dwEndLo (ascending-i)
            int kdl = 0;
            int e8 = dwEndLo < 8 ? dwEndLo : 8;
            for (; kdl < e8; ++kdl)      { unsigned d; FETCH8(vLoA, kdl, d);     GLO4(d, kdl); }
            for (; kdl < dwEndLo; ++kdl) { unsigned d; FETCH8(vLoB, kdl - 8, d); GLO4(d, kdl); }

            // hi phase: consume window 4-wide, reissue
            int kc = 0;
            for (; kc + 4 <= dwEndHi; kc += 4) {
                WCON(0); WISS(0);
                WCON(1); WISS(1);
                WCON(2); WISS(2);
                WCON(3); WISS(3);
            }
            int rem = dwEndHi - kc;
            if (rem > 0) WCON(0);
            if (rem > 1) WCON(1);
            if (rem > 2) WCON(2);

            // exchange: every lane gets h(t+0..t+7) for its quad
            sEx[wave][lane] = h4;
            e0 = sEx[wave][q];      e1 = sEx[wave][8 + q];
            e2 = sEx[wave][16 + q]; e3 = sEx[wave][24 + q];
            e4 = sEx[wave][32 + q]; e5 = sEx[wave][40 + q];
            e6 = sEx[wave][48 + q]; e7 = sEx[wave][56 + q];
        } else {
            // ~never: overflow -> recompute all 8 t's from x (ascending i, global)
#pragma unroll
            for (int tt = 0; tt < 8; ++tt) {
                const float* xr = x + ((size_t)(t + tt) * BB + ub) * NIN;
                f4 g = bs;
                for (int w2 = 0; w2 < 4; ++w2) {
                    unsigned long long m = __ballot(xr[(w2 << 6) + lane] > 0.5f);
                    while (m) {
                        int i = (w2 << 6) + __builtin_ctzll(m);
                        m &= m - 1;
                        g += W1Tf4[((unsigned)i << 8) + jq4];
                    }
                }
                if      (tt == 0) e0 = g; else if (tt == 1) e1 = g;
                else if (tt == 2) e2 = g; else if (tt == 3) e3 = g;
                else if (tt == 4) e4 = g; else if (tt == 5) e5 = g;
                else if (tt == 6) e6 = g; else              e7 = g;
            }
        }

        // 8 membrane steps (np fp32 semantics: mul, add separate; packed ops
        // per-slot IEEE), redundant across lanes so exec stays full.
        f4 k0, k1, k2, k3, k4, k5, k6, k7;
        MSTEP(e0, k0) MSTEP(e1, k1) MSTEP(e2, k2) MSTEP(e3, k3)
        MSTEP(e4, k4) MSTEP(e5, k5) MSTEP(e6, k6) MSTEP(e7, k7)

        // lane stores its own group's row (t+s)
        f4 a0 = sb0 ? k1 : k0, a1 = sb0 ? k3 : k2;
        f4 a2 = sb0 ? k5 : k4, a3 = sb0 ? k7 : k6;
        f4 b0 = sb1 ? a1 : a0, b1v = sb1 ? a3 : a2;
        f4 sv = sb2 ? b1v : b0;
        *reinterpret_cast<f4*>(outP) = sv;
        outP += outStep;
    }
#undef MSTEP
#undef WCON
#undef WISS
#undef FETCH_HI
#undef GLO4
#undef FETCH8
#undef RL
}

// One wave per (t,b): bit-identical layer-2 tree to rounds 1-14.
__global__ __launch_bounds__(256) void k_h2(const float* __restrict__ spk,
                                            const float* __restrict__ W2,
                                            const float* __restrict__ b2,
                                            float* __restrict__ h2) {
#pragma clang fp contract(off)
    const int lane = threadIdx.x & 63;
    const int wave = threadIdx.x >> 6;
    size_t tb = (size_t)blockIdx.x * 4 + wave;    // t*B + b
    const float* row = spk + tb * HID;
    float s0 = 0.0f, s1 = 0.0f;
#pragma unroll
    for (int c = 0; c < 16; ++c) {
        float v  = row[c * 64 + lane];
        float r0 = v * W2[c * 64 + lane];
        float r1 = v * W2[HID + c * 64 + lane];
#pragma unroll
        for (int off = 32; off > 0; off >>= 1) {
            r0 += __shfl_xor(r0, off, 64);
            r1 += __shfl_xor(r1, off, 64);
        }
        s0 += r0;
        s1 += r1;
    }
    s0 += b2[0];
    s1 += b2[1];
    if (lane == 0)
        *reinterpret_cast<float2*>(h2 + tb * 2) = make_float2(s0, s1);
}

__global__ __launch_bounds__(256) void k_scan(const float* __restrict__ h2,
                                              float* __restrict__ outSpk,
                                              float* __restrict__ outMem2) {
#pragma clang fp contract(off)
    const int tid = threadIdx.x;                  // b*2 + o
    float mem = 0.0f;
    float cur[8], nxt[8];
#pragma unroll
    for (int k = 0; k < 8; ++k) cur[k] = h2[k * 256 + tid];
    for (int t0 = 0; t0 < TT; t0 += 8) {
#pragma unroll
        for (int k = 0; k < 8; ++k) {
            int tn = t0 + 8 + k;
            nxt[k] = (tn < TT) ? h2[tn * 256 + tid] : 0.0f;
        }
#pragma unroll
        for (int k = 0; k < 8; ++k) {
            float mm = 0.9f * mem;
            mm = mm + cur[k];
            float spk = (mm - 1.0f > 0.0f) ? 1.0f : 0.0f;
            mm = mm - spk;
            mem = mm;
            outSpk[(t0 + k) * 256 + tid] = spk;
        }
#pragma unroll
        for (int k = 0; k < 8; ++k) cur[k] = nxt[k];
    }
    outMem2[tid] = mem;
}

extern "C" void kernel_launch(void* const* d_in, const int* in_sizes, int n_in,
                              void* d_out, int out_size, void* d_ws, size_t ws_size,
                              hipStream_t stream) {
    const float* x  = (const float*)d_in[0];
    const float* W1 = (const float*)d_in[1];
    const float* b1 = (const float*)d_in[2];
    const float* W2 = (const float*)d_in[3];
    const float* b2 = (const float*)d_in[4];
    float* out = (float*)d_out;

    char* ws = (char*)d_ws;                       // ~19.5 MB used
    float*         W1T = (float*)(ws);                                  // 1.03 MB (reserve 2MB)
    unsigned*      cnt = (unsigned*)(ws + (2 << 20));                   // 512 KB
    unsigned char* idx = (unsigned char*)(ws + (2 << 20) + (1 << 19));  // 131072*128 = 16 MB
    float*         h2  = (float*)(ws + (2 << 20) + (1 << 19) + (16 << 20)); // 1 MB

    k_transpose<<<1028, 256, 0, stream>>>(W1, W1T);
    k_pack<<<131072, 256, 0, stream>>>(x, cnt, idx);
    k_snn<<<1024, 256, 0, stream>>>(W1T, cnt, idx, x, b1, out + OFF_HID);
    k_h2<<<32768, 256, 0, stream>>>(out + OFF_HID, W2, b2, h2);
    k_scan<<<1, 256, 0, stream>>>(h2, out, out + OFF_MEM2);
}